// Round 11
// baseline (300.193 us; speedup 1.0000x reference)
//
#include <hip/hip_runtime.h>

#define HW_ELEMS (512 * 512)            // elements per (n,c) channel
#define HW4      (HW_ELEMS / 4)         // 65536 fx4 per channel
#define NC 192
#define THREADS 256
#define TEAM 16                         // blocks per channel (team)
#define SL4 (HW4 / TEAM)                // 4096 fx4 per block-slice (64 KB)
#define PT (SL4 / THREADS)              // 16 fx4 per thread
#define GRID 512                        // = 2 blocks/CU, exactly co-resident
#define ROUNDS (NC * TEAM / GRID)       // 6
#define EPS 1e-8f
#define SMEM_BYTES (SL4 * 16 + 64)      // staging + reduction scratch

typedef float fx4 __attribute__((ext_vector_type(4)));

// LDS-staged fused instance norm.
// R8/R10 lesson: the compiler rematerializes global loads rather than hold
// payload registers across barriers, so reg-resident schemes collapse to a
// load+store-coupled vmcnt queue (~2.4 TB/s). LDS staging decouples the
// streams: phase-1 vmcnt holds ONLY global loads (ds_write counts in
// lgkmcnt), phase-2 vmcnt holds ONLY nt stores (ds_read is lgkmcnt), and
// LDS contents cannot be rematerialized away.
__global__ __launch_bounds__(THREADS, 2) void instnorm_lds(
    const float* __restrict__ in, float* __restrict__ out,
    float* __restrict__ psum, float* __restrict__ psq,
    unsigned* __restrict__ sem)
{
    extern __shared__ char smem[];
    fx4*   lds4  = reinterpret_cast<fx4*>(smem);
    float* s_red = reinterpret_cast<float*>(smem + SL4 * 16);  // 8 floats
    float* s_ms  = s_red + 8;                                   // mean, rstd
    const int t = threadIdx.x;

    for (int r = 0; r < ROUNDS; ++r) {
        const int c = r * (GRID / TEAM) + (blockIdx.x >> 4);   // channel
        const int b = blockIdx.x & (TEAM - 1);                 // slice in team
        const size_t base = (size_t)c * HW4 + (size_t)b * SL4;
        const fx4* p = reinterpret_cast<const fx4*>(in) + base;

        // ---- phase 1: global -> reg (stats) -> LDS; vmcnt = loads only ----
        float sum = 0.f, sq = 0.f;
        fx4 v[PT];
#pragma unroll
        for (int u = 0; u < PT; ++u)
            v[u] = p[t + u * THREADS];
#pragma unroll
        for (int u = 0; u < PT; ++u) {
            lds4[t + u * THREADS] = v[u];
            sum += (v[u].x + v[u].y) + (v[u].z + v[u].w);
            sq  += v[u].x * v[u].x + v[u].y * v[u].y
                 + v[u].z * v[u].z + v[u].w * v[u].w;
        }
#pragma unroll
        for (int off = 32; off > 0; off >>= 1) {
            sum += __shfl_down(sum, off, 64);
            sq  += __shfl_down(sq,  off, 64);
        }
        if ((t & 63) == 0) { s_red[t >> 6] = sum; s_red[4 + (t >> 6)] = sq; }
        __syncthreads();

        // ---- t0: publish partial, team-sync (relaxed spin), combine ----
        if (t == 0) {
            float S = s_red[0] + s_red[1] + s_red[2] + s_red[3];
            float Q = s_red[4] + s_red[5] + s_red[6] + s_red[7];
            const int s = c * TEAM + b;
            __hip_atomic_store(&psum[s], S, __ATOMIC_RELAXED, __HIP_MEMORY_SCOPE_AGENT);
            __hip_atomic_store(&psq[s],  Q, __ATOMIC_RELAXED, __HIP_MEMORY_SCOPE_AGENT);
            __hip_atomic_fetch_add(&sem[c], 1u, __ATOMIC_RELEASE, __HIP_MEMORY_SCOPE_AGENT);
            while (__hip_atomic_load(&sem[c], __ATOMIC_RELAXED, __HIP_MEMORY_SCOPE_AGENT) < TEAM)
                __builtin_amdgcn_s_sleep(1);
            float Sa = 0.f, Qa = 0.f;
#pragma unroll
            for (int i = 0; i < TEAM; ++i) {
                Sa += __hip_atomic_load(&psum[c * TEAM + i], __ATOMIC_RELAXED, __HIP_MEMORY_SCOPE_AGENT);
                Qa += __hip_atomic_load(&psq[c * TEAM + i],  __ATOMIC_RELAXED, __HIP_MEMORY_SCOPE_AGENT);
            }
            const float n = (float)HW_ELEMS;
            float mean = Sa / n;
            float var  = (Qa - Sa * Sa / n) / (n - 1.0f);      // ddof=1
            if (var < 0.f) var = 0.f;
            s_ms[0] = mean;
            s_ms[1] = 1.0f / (sqrtf(var) + EPS);
        }
        __syncthreads();
        const float mean = s_ms[0];
        const float rstd = s_ms[1];

        // ---- phase 2: LDS -> normalize -> nt store; vmcnt = stores only ----
#pragma unroll
        for (int u = 0; u < PT; ++u) {
            fx4 w = lds4[t + u * THREADS];
            fx4 rr = (w - mean) * rstd;
            __builtin_nontemporal_store(
                rr, reinterpret_cast<fx4*>(out) + base + t + u * THREADS);
        }
        __syncthreads();   // all LDS reads done before next round's writes
    }
}

// ---------- fallback path (two-kernel, R3-proven 91 us) ----------
#define BPC_FB 8
__global__ __launch_bounds__(256) void instnorm_partial(
    const float* __restrict__ in, float* __restrict__ psum, float* __restrict__ psq)
{
    const int c = blockIdx.x >> 3;
    const int b = blockIdx.x & (BPC_FB - 1);
    const fx4* p = reinterpret_cast<const fx4*>(in)
                 + (size_t)c * HW4 + (size_t)b * (HW4 / BPC_FB);
    const int t = threadIdx.x;
    float sum = 0.f, sq = 0.f;
#pragma unroll
    for (int k = 0; k < HW4 / BPC_FB / 256; ++k) {
        fx4 v = p[t + k * 256];
        sum += (v.x + v.y) + (v.z + v.w);
        sq  += v.x * v.x + v.y * v.y + v.z * v.z + v.w * v.w;
    }
#pragma unroll
    for (int off = 32; off > 0; off >>= 1) {
        sum += __shfl_down(sum, off, 64);
        sq  += __shfl_down(sq,  off, 64);
    }
    __shared__ float s_red[8];
    if ((t & 63) == 0) { s_red[t >> 6] = sum; s_red[4 + (t >> 6)] = sq; }
    __syncthreads();
    if (t == 0) {
        psum[blockIdx.x] = s_red[0] + s_red[1] + s_red[2] + s_red[3];
        psq[blockIdx.x]  = s_red[4] + s_red[5] + s_red[6] + s_red[7];
    }
}

__global__ __launch_bounds__(256) void instnorm_apply(
    const float* __restrict__ in, float* __restrict__ out,
    const float* __restrict__ psum, const float* __restrict__ psq)
{
    const int c = blockIdx.x >> 8;
    float S = 0.f, Q = 0.f;
#pragma unroll
    for (int i = 0; i < BPC_FB; ++i) { S += psum[c * BPC_FB + i]; Q += psq[c * BPC_FB + i]; }
    const float n = (float)HW_ELEMS;
    float mean = S / n;
    float var  = (Q - S * S / n) / (n - 1.0f);
    if (var < 0.f) var = 0.f;
    float rstd = 1.0f / (sqrtf(var) + EPS);

    const size_t i4 = (size_t)blockIdx.x * 256 + threadIdx.x;
    fx4 v = reinterpret_cast<const fx4*>(in)[i4];
    fx4 r = (v - mean) * rstd;
    __builtin_nontemporal_store(r, reinterpret_cast<fx4*>(out) + i4);
}

extern "C" void kernel_launch(void* const* d_in, const int* in_sizes, int n_in,
                              void* d_out, int out_size, void* d_ws, size_t ws_size,
                              hipStream_t stream) {
    const float* in = (const float*)d_in[0];
    float* out = (float*)d_out;
    // ws layout: psum[NC*TEAM] | psq[NC*TEAM] | sem[NC]
    float*    psum = (float*)d_ws;
    float*    psq  = psum + NC * TEAM;
    unsigned* sem  = (unsigned*)(psq + NC * TEAM);

    hipMemsetAsync(sem, 0, NC * sizeof(unsigned), stream);

    void* args[] = { (void*)&in, (void*)&out, (void*)&psum, (void*)&psq, (void*)&sem };
    hipError_t rc = hipLaunchCooperativeKernel((const void*)instnorm_lds,
                                               dim3(GRID), dim3(THREADS),
                                               args, SMEM_BYTES, stream);
    if (rc != hipSuccess) {
        // Fallback: proven two-kernel path (uses psum/psq only, sized NC*BPC_FB)
        instnorm_partial<<<NC * BPC_FB, 256, 0, stream>>>(in, psum, psq);
        const size_t total4 = (size_t)NC * HW4;
        instnorm_apply<<<(int)(total4 / 256), 256, 0, stream>>>(in, out, psum, psq);
    }
}